// Round 1
// baseline (299.333 us; speedup 1.0000x reference)
//
#include <hip/hip_runtime.h>

#define HD 1024
#define FD 2816
#define NE 8
#define NT 1024

#define BM 128
#define BN 64
#define BK 32
#define APAD 40   // padded k-stride (elements) to break LDS bank conflicts

typedef short short8 __attribute__((ext_vector_type(8)));
typedef short short4v __attribute__((ext_vector_type(4)));
typedef float f32x4 __attribute__((ext_vector_type(4)));

__device__ inline short f2bf(float f) {
  unsigned u = __builtin_bit_cast(unsigned, f);
  u += 0x7FFFu + ((u >> 16) & 1u);   // round-to-nearest-even
  return (short)(u >> 16);
}

// ---------------- router: logits -> softmax -> top2 -> normalized weights ---
__global__ void router_kernel(const float* __restrict__ x,
                              const float* __restrict__ rw,
                              int* __restrict__ counts,
                              int* __restrict__ tok_i,
                              float* __restrict__ tok_w) {
  const int t = blockIdx.x;
  const int lane = threadIdx.x;
  const float* px = x + (size_t)t * HD;
  float acc[NE];
#pragma unroll
  for (int e = 0; e < NE; e++) acc[e] = 0.f;
  for (int h = lane; h < HD; h += 64) {
    float xv = px[h];
#pragma unroll
    for (int e = 0; e < NE; e++) acc[e] += xv * rw[e * HD + h];
  }
#pragma unroll
  for (int e = 0; e < NE; e++) {
#pragma unroll
    for (int off = 32; off > 0; off >>= 1)
      acc[e] += __shfl_xor(acc[e], off, 64);
  }
  if (lane == 0) {
    float mx = acc[0];
#pragma unroll
    for (int e = 1; e < NE; e++) mx = fmaxf(mx, acc[e]);
    float ex[NE];
#pragma unroll
    for (int e = 0; e < NE; e++) ex[e] = __expf(acc[e] - mx);
    int i1 = 0;
#pragma unroll
    for (int e = 1; e < NE; e++) if (ex[e] > ex[i1]) i1 = e;
    int i2 = (i1 == 0) ? 1 : 0;
#pragma unroll
    for (int e = 0; e < NE; e++) if (e != i1 && ex[e] > ex[i2]) i2 = e;
    float inv = 1.f / (ex[i1] + ex[i2]);   // softmax denom cancels in topk-norm
    tok_i[t * 2 + 0] = i1; tok_w[t * 2 + 0] = ex[i1] * inv;
    tok_i[t * 2 + 1] = i2; tok_w[t * 2 + 1] = ex[i2] * inv;
    atomicAdd(&counts[i1], 1);
    atomicAdd(&counts[i2], 1);
  }
}

// ---------------- prefix sum over 8 experts --------------------------------
__global__ void scan_kernel(const int* __restrict__ counts,
                            int* __restrict__ bases,
                            int* __restrict__ cursor) {
  if (threadIdx.x == 0) {
    int s = 0;
    for (int e = 0; e < NE; e++) { bases[e] = s; cursor[e] = s; s += counts[e]; }
    bases[NE] = s;
  }
}

// ---------------- build compact per-expert token lists ---------------------
__global__ void fill_kernel(const int* __restrict__ tok_i,
                            const float* __restrict__ tok_w,
                            int* __restrict__ cursor,
                            int* __restrict__ slot_token,
                            float* __restrict__ slot_w,
                            int* __restrict__ slot_of) {
  int t = blockIdx.x * 256 + threadIdx.x;
  if (t >= NT) return;
#pragma unroll
  for (int k = 0; k < 2; k++) {
    int e = tok_i[t * 2 + k];
    int pos = atomicAdd(&cursor[e], 1);
    slot_token[pos] = t;
    slot_w[pos] = tok_w[t * 2 + k];
    slot_of[t * 2 + k] = pos;
  }
}

// ---------------- grouped gate+up GEMM, fused silu*mul, bf16 out -----------
// grid: (FD/BN, NT/BM, NE), block 256
__global__ __launch_bounds__(256) void gateup_kernel(
    const float* __restrict__ x,
    const float* __restrict__ gate_w,
    const float* __restrict__ up_w,
    const int* __restrict__ bases,
    const int* __restrict__ slot_token,
    short* __restrict__ m_out) {
  const int e = blockIdx.z;
  const int b0 = bases[e];
  const int ne = bases[e + 1] - b0;
  const int row0 = blockIdx.y * BM;
  if (row0 >= ne) return;
  const int n0 = blockIdx.x * BN;

  __shared__ short As[BM * APAD];
  __shared__ short Bs[2][BN * APAD];

  const int tid = threadIdx.x;
  // A staging: 128 rows x 2 half-rows of 16 k
  const int arow = tid >> 1;
  const int ahalf = tid & 1;
  const int rA = row0 + arow;
  const int tok = slot_token[b0 + (rA < ne ? rA : 0)];
  const float* pxa = x + (size_t)tok * HD + ahalf * 16;
  // B staging: 2 matrices x (16 f-quads x 8 k-quads), 4x4 reg transpose
  const int mat = tid >> 7;
  const int rr = tid & 127;
  const int fq = rr & 15;
  const int kq = rr >> 4;
  const float* wbase =
      (mat ? up_w : gate_w) + (size_t)e * HD * FD + n0 + fq * 4;

  const int lane = tid & 63;
  const int wid = tid >> 6;
  const int wm = wid >> 1;
  const int wn = wid & 1;
  const int l15 = lane & 15;
  const int l4 = lane >> 4;

  f32x4 accG[4][2], accU[4][2];
#pragma unroll
  for (int mi = 0; mi < 4; mi++)
#pragma unroll
    for (int ni = 0; ni < 2; ni++) {
      accG[mi][ni] = (f32x4)0.f;
      accU[mi][ni] = (f32x4)0.f;
    }

  for (int k0 = 0; k0 < HD; k0 += BK) {
    f32x4 av[4];
#pragma unroll
    for (int i = 0; i < 4; i++)
      av[i] = *(const f32x4*)(pxa + k0 + i * 4);
    f32x4 bv[4];
#pragma unroll
    for (int kk = 0; kk < 4; kk++)
      bv[kk] = *(const f32x4*)(wbase + (size_t)(k0 + kq * 4 + kk) * FD);

    __syncthreads();   // previous iteration's LDS reads done
    short8 a0, a1;
#pragma unroll
    for (int j = 0; j < 8; j++) {
      a0[j] = f2bf(av[j >> 2][j & 3]);
      a1[j] = f2bf(av[(j >> 2) + 2][j & 3]);
    }
    *(short8*)&As[arow * APAD + ahalf * 16] = a0;
    *(short8*)&As[arow * APAD + ahalf * 16 + 8] = a1;
#pragma unroll
    for (int ff = 0; ff < 4; ff++) {
      short4v wv;
      wv[0] = f2bf(bv[0][ff]); wv[1] = f2bf(bv[1][ff]);
      wv[2] = f2bf(bv[2][ff]); wv[3] = f2bf(bv[3][ff]);
      *(short4v*)&Bs[mat][(fq * 4 + ff) * APAD + kq * 4] = wv;
    }
    __syncthreads();

    short8 af[4];
#pragma unroll
    for (int mi = 0; mi < 4; mi++)
      af[mi] = *(short8*)&As[(wm * 64 + mi * 16 + l15) * APAD + l4 * 8];
    short8 bg[2], bu[2];
#pragma unroll
    for (int ni = 0; ni < 2; ni++) {
      bg[ni] = *(short8*)&Bs[0][(wn * 32 + ni * 16 + l15) * APAD + l4 * 8];
      bu[ni] = *(short8*)&Bs[1][(wn * 32 + ni * 16 + l15) * APAD + l4 * 8];
    }
#pragma unroll
    for (int mi = 0; mi < 4; mi++)
#pragma unroll
      for (int ni = 0; ni < 2; ni++) {
        accG[mi][ni] = __builtin_amdgcn_mfma_f32_16x16x32_bf16(
            af[mi], bg[ni], accG[mi][ni], 0, 0, 0);
        accU[mi][ni] = __builtin_amdgcn_mfma_f32_16x16x32_bf16(
            af[mi], bu[ni], accU[mi][ni], 0, 0, 0);
      }
  }

#pragma unroll
  for (int mi = 0; mi < 4; mi++)
#pragma unroll
    for (int ni = 0; ni < 2; ni++)
#pragma unroll
      for (int r = 0; r < 4; r++) {
        int row = row0 + wm * 64 + mi * 16 + l4 * 4 + r;
        if (row < ne) {
          float g = accG[mi][ni][r];
          float u = accU[mi][ni][r];
          float mv = (g / (1.f + __expf(-g))) * u;
          int f = n0 + wn * 32 + ni * 16 + l15;
          m_out[(size_t)(b0 + row) * FD + f] = f2bf(mv);
        }
      }
}

// ---------------- grouped down GEMM, scaled by routing weight --------------
// grid: (HD/BN, NT/BM, NE), block 256
__global__ __launch_bounds__(256) void down_kernel(
    const short* __restrict__ m_in,
    const float* __restrict__ down_w,
    const int* __restrict__ bases,
    const float* __restrict__ slot_w,
    float* __restrict__ out_slot) {
  const int e = blockIdx.z;
  const int b0 = bases[e];
  const int ne = bases[e + 1] - b0;
  const int row0 = blockIdx.y * BM;
  if (row0 >= ne) return;
  const int n0 = blockIdx.x * BN;

  __shared__ short As[BM * APAD];
  __shared__ short Bs[BN * APAD];

  const int tid = threadIdx.x;
  const int arow = tid >> 1;
  const int ahalf = tid & 1;
  const int rA = row0 + arow;
  const int slotA = b0 + (rA < ne ? rA : 0);
  const short* pma = m_in + (size_t)slotA * FD + ahalf * 16;

  const int fq = tid & 15;   // h-quad (only tid<128 stages B)
  const int kq = (tid & 127) >> 4;
  const float* wbase = down_w + (size_t)e * FD * HD + n0 + fq * 4;

  const int lane = tid & 63;
  const int wid = tid >> 6;
  const int wm = wid >> 1;
  const int wn = wid & 1;
  const int l15 = lane & 15;
  const int l4 = lane >> 4;

  f32x4 acc[4][2];
#pragma unroll
  for (int mi = 0; mi < 4; mi++)
#pragma unroll
    for (int ni = 0; ni < 2; ni++) acc[mi][ni] = (f32x4)0.f;

  for (int k0 = 0; k0 < FD; k0 += BK) {   // 88 steps over F
    short8 am0 = *(const short8*)(pma + k0);
    short8 am1 = *(const short8*)(pma + k0 + 8);
    f32x4 bv[4];
    if (tid < 128) {
#pragma unroll
      for (int kk = 0; kk < 4; kk++)
        bv[kk] = *(const f32x4*)(wbase + (size_t)(k0 + kq * 4 + kk) * HD);
    }
    __syncthreads();
    *(short8*)&As[arow * APAD + ahalf * 16] = am0;
    *(short8*)&As[arow * APAD + ahalf * 16 + 8] = am1;
    if (tid < 128) {
#pragma unroll
      for (int ff = 0; ff < 4; ff++) {
        short4v wv;
        wv[0] = f2bf(bv[0][ff]); wv[1] = f2bf(bv[1][ff]);
        wv[2] = f2bf(bv[2][ff]); wv[3] = f2bf(bv[3][ff]);
        *(short4v*)&Bs[(fq * 4 + ff) * APAD + kq * 4] = wv;
      }
    }
    __syncthreads();

    short8 af[4];
#pragma unroll
    for (int mi = 0; mi < 4; mi++)
      af[mi] = *(short8*)&As[(wm * 64 + mi * 16 + l15) * APAD + l4 * 8];
    short8 bf[2];
#pragma unroll
    for (int ni = 0; ni < 2; ni++)
      bf[ni] = *(short8*)&Bs[(wn * 32 + ni * 16 + l15) * APAD + l4 * 8];
#pragma unroll
    for (int mi = 0; mi < 4; mi++)
#pragma unroll
      for (int ni = 0; ni < 2; ni++)
        acc[mi][ni] = __builtin_amdgcn_mfma_f32_16x16x32_bf16(
            af[mi], bf[ni], acc[mi][ni], 0, 0, 0);
  }

#pragma unroll
  for (int mi = 0; mi < 4; mi++)
#pragma unroll
    for (int ni = 0; ni < 2; ni++)
#pragma unroll
      for (int r = 0; r < 4; r++) {
        int row = row0 + wm * 64 + mi * 16 + l4 * 4 + r;
        if (row < ne) {
          int slot = b0 + row;
          float w = slot_w[slot];
          int h = n0 + wn * 32 + ni * 16 + l15;
          out_slot[(size_t)slot * HD + h] = acc[mi][ni][r] * w;
        }
      }
}

// ---------------- combine the 2 slots of each token ------------------------
__global__ void combine_kernel(const float* __restrict__ out_slot,
                               const int* __restrict__ slot_of,
                               float* __restrict__ out) {
  const int t = blockIdx.x;
  const int s0 = slot_of[t * 2];
  const int s1 = slot_of[t * 2 + 1];
  const int i = threadIdx.x * 4;
  f32x4 a = *(const f32x4*)(out_slot + (size_t)s0 * HD + i);
  f32x4 b = *(const f32x4*)(out_slot + (size_t)s1 * HD + i);
  f32x4 c = a + b;
  *(f32x4*)(out + (size_t)t * HD + i) = c;
}

extern "C" void kernel_launch(void* const* d_in, const int* in_sizes, int n_in,
                              void* d_out, int out_size, void* d_ws,
                              size_t ws_size, hipStream_t stream) {
  const float* x = (const float*)d_in[0];
  const float* rw = (const float*)d_in[1];
  const float* gw = (const float*)d_in[2];
  const float* uw = (const float*)d_in[3];
  const float* dw = (const float*)d_in[4];
  float* out = (float*)d_out;

  char* ws = (char*)d_ws;
  int* counts = (int*)(ws + 0);
  int* cursor = (int*)(ws + 64);
  int* bases = (int*)(ws + 128);
  int* tok_i = (int*)(ws + 256);
  float* tok_w = (float*)(ws + 256 + 8192);
  int* slot_token = (int*)(ws + 256 + 16384);
  float* slot_w = (float*)(ws + 256 + 24576);
  int* slot_of = (int*)(ws + 256 + 32768);
  short* m_buf = (short*)(ws + 41216);                 // 2048 x 2816 bf16
  float* out_slot = (float*)(ws + 41216 + 11534336);   // 2048 x 1024 f32

  hipMemsetAsync(counts, 0, 64, stream);
  router_kernel<<<NT, 64, 0, stream>>>(x, rw, counts, tok_i, tok_w);
  scan_kernel<<<1, 64, 0, stream>>>(counts, bases, cursor);
  fill_kernel<<<NT / 256, 256, 0, stream>>>(tok_i, tok_w, cursor, slot_token,
                                            slot_w, slot_of);
  gateup_kernel<<<dim3(FD / BN, NT / BM, NE), 256, 0, stream>>>(
      x, gw, uw, bases, slot_token, m_buf);
  down_kernel<<<dim3(HD / BN, NT / BM, NE), 256, 0, stream>>>(
      m_buf, dw, bases, slot_w, out_slot);
  combine_kernel<<<NT, 256, 0, stream>>>(out_slot, slot_of, out);
}